// Round 8
// baseline (828.383 us; speedup 1.0000x reference)
//
#include <hip/hip_runtime.h>
#include <stdint.h>

#define HDIM 2048
#define NC   12
#define NL   32
#define NBLK 256     // EXACTLY 256 blocks (1/CU) — proven-launchable config
#define NTHR 512     // 8 waves/block; wave (blk*8+wv) owns h-position j
#define NWAVE 8
#define FLAGMAGIC 0x600DF00Du
#define SPINCAP   2000000       // bounded spin: bug => wrong answer, not hang

// ---------------- Threefry-2x32 (20 rounds), JAX partitionable path (verified r4) ----
__device__ __forceinline__ uint32_t rotl32(uint32_t x, int r) {
  return (x << r) | (x >> (32 - r));
}
__device__ __forceinline__ void tf2x32(uint32_t k0, uint32_t k1,
                                       uint32_t &x0, uint32_t &x1) {
  const uint32_t ks2 = k0 ^ k1 ^ 0x1BD11BDAu;
  x0 += k0; x1 += k1;
#define TFR(r) { x0 += x1; x1 = rotl32(x1, (r)); x1 ^= x0; }
  TFR(13) TFR(15) TFR(26) TFR(6)   x0 += k1;  x1 += ks2 + 1u;
  TFR(17) TFR(29) TFR(16) TFR(24)  x0 += ks2; x1 += k0  + 2u;
  TFR(13) TFR(15) TFR(26) TFR(6)   x0 += k0;  x1 += k1  + 3u;
  TFR(17) TFR(29) TFR(16) TFR(24)  x0 += k1;  x1 += ks2 + 4u;
  TFR(13) TFR(15) TFR(26) TFR(6)   x0 += ks2; x1 += k0  + 5u;
#undef TFR
}

// ---- relaxed agent-scope atomics: device-coherent per access, no cache-wide maintenance ----
__device__ __forceinline__ uint32_t ald(const uint32_t* p) {
  return __hip_atomic_load(p, __ATOMIC_RELAXED, __HIP_MEMORY_SCOPE_AGENT);
}
__device__ __forceinline__ void ast(uint32_t* p, uint32_t v) {
  __hip_atomic_store(p, v, __ATOMIC_RELAXED, __HIP_MEMORY_SCOPE_AGENT);
}
__device__ __forceinline__ float aldf(const float* p) {
  return __uint_as_float(__hip_atomic_load((const uint32_t*)p, __ATOMIC_RELAXED, __HIP_MEMORY_SCOPE_AGENT));
}
__device__ __forceinline__ void astf(float* p, float v) {
  __hip_atomic_store((uint32_t*)p, __float_as_uint(v), __ATOMIC_RELAXED, __HIP_MEMORY_SCOPE_AGENT);
}
__device__ __forceinline__ uint64_t ald64(const uint64_t* p) {
  return __hip_atomic_load(p, __ATOMIC_RELAXED, __HIP_MEMORY_SCOPE_AGENT);
}
#define VMCNT0() asm volatile("s_waitcnt vmcnt(0)" ::: "memory")
#define CFENCE() asm volatile("" ::: "memory")

// ws layout (floats): h_buf[2][HDIM] | partials[2][NC][NBLK] | flags u32[NL][NBLK]
// ~72 KB. Sync words written once per launch; 0xAAAAAAAA poison never matches FLAGMAGIC.
__global__ void __launch_bounds__(NTHR, 2) ctrl_kernel(
    const float* __restrict__ prev_c, const float* __restrict__ prev_h,
    const float* __restrict__ encoder, const float* __restrict__ w_ih,
    const float* __restrict__ w_hh, const float* __restrict__ b_ih,
    const float* __restrict__ b_hh, const float* __restrict__ w_soft,
    float* __restrict__ out, float* __restrict__ ws)
{
  const int tid  = threadIdx.x;
  const int lane = tid & 63;
  const int wv   = tid >> 6;
  const int blk  = blockIdx.x;
  const int j    = blk * NWAVE + wv;                   // owned h-position

  float*    hbF    = ws;                               // [2][HDIM]
  float*    partF  = ws + 2 * HDIM;                    // [2][NC*NBLK], [c][b] planes
  uint32_t* flagsU = (uint32_t*)(ws + 2 * HDIM + 2 * NC * NBLK);  // [NL][NBLK]

  __shared__ __align__(16) float s_h[HDIM];
  __shared__ float s_E[NWAVE][4][NC];
  __shared__ float s_part[NWAVE][NC];
  __shared__ int   s_op;

  // one-time E[c][g] = encoder[c] . w_ih_row(g,j) + b_ih + b_hh  (w_ih read exactly once)
  {
    float4 wif[4][8];
    #pragma unroll
    for (int g = 0; g < 4; ++g) {
      const float4* wp = reinterpret_cast<const float4*>(w_ih + (size_t)(g * HDIM + j) * HDIM);
      #pragma unroll
      for (int k = 0; k < 8; ++k) wif[g][k] = wp[k * 64 + lane];
    }
    float bsum[4];
    #pragma unroll
    for (int g = 0; g < 4; ++g) bsum[g] = b_ih[g * HDIM + j] + b_hh[g * HDIM + j];

    for (int c = 0; c < NC; ++c) {
      const float4* ep = reinterpret_cast<const float4*>(encoder + (size_t)c * HDIM);
      float s0 = 0.f, s1 = 0.f, s2 = 0.f, s3 = 0.f;
      #pragma unroll
      for (int k = 0; k < 8; ++k) {
        float4 e = ep[k * 64 + lane];
        s0 += wif[0][k].x*e.x + wif[0][k].y*e.y + wif[0][k].z*e.z + wif[0][k].w*e.w;
        s1 += wif[1][k].x*e.x + wif[1][k].y*e.y + wif[1][k].z*e.z + wif[1][k].w*e.w;
        s2 += wif[2][k].x*e.x + wif[2][k].y*e.y + wif[2][k].z*e.z + wif[2][k].w*e.w;
        s3 += wif[3][k].x*e.x + wif[3][k].y*e.y + wif[3][k].z*e.z + wif[3][k].w*e.w;
      }
      #pragma unroll
      for (int d = 1; d < 64; d <<= 1) {
        s0 += __shfl_xor(s0, d, 64); s1 += __shfl_xor(s1, d, 64);
        s2 += __shfl_xor(s2, d, 64); s3 += __shfl_xor(s3, d, 64);
      }
      if (lane == 0) {
        s_E[wv][0][c] = s0 + bsum[0]; s_E[wv][1][c] = s1 + bsum[1];
        s_E[wv][2][c] = s2 + bsum[2]; s_E[wv][3][c] = s3 + bsum[3];
      }
    }
  }
  __syncthreads();

  const float wsj = (lane < NC) ? w_soft[(size_t)lane * HDIM + j] : 0.f;
  float c_val   = prev_c[j];
  float nll_acc = 0.f, ent_acc = 0.f;                  // meaningful in blk0/wv0/lane0 only

  for (int t = 0; t < NL; ++t) {
    float pp0[NC], pp1[NC], pp2[NC], pp3[NC];          // wv0: prefetched partials(t-1)

    // ---- wait for flags(t-1); prefetch partials(t-1); stage h(t-1) ----
    if (t > 0) {
      if (wv == 0) {
        const uint32_t* f = flagsU + (size_t)(t - 1) * NBLK;
        for (int it = 0; it < SPINCAP; ++it) {
          uint32_t a0 = ald(f + lane), a1 = ald(f + lane + 64),
                   a2 = ald(f + lane + 128), a3 = ald(f + lane + 192);
          bool ok = (a0 == FLAGMAGIC) & (a1 == FLAGMAGIC) & (a2 == FLAGMAGIC) & (a3 == FLAGMAGIC);
          if (__all(ok)) break;
        }
        CFENCE();
        // prefetch the 12 partial planes (issued now; latency absorbed with h staging)
        const float* pb = partF + ((t - 1) & 1) * (NC * NBLK);
        #pragma unroll
        for (int c = 0; c < NC; ++c) {
          pp0[c] = aldf(pb + c * NBLK + lane);
          pp1[c] = aldf(pb + c * NBLK + lane + 64);
          pp2[c] = aldf(pb + c * NBLK + lane + 128);
          pp3[c] = aldf(pb + c * NBLK + lane + 192);
        }
      }
      __syncthreads();
      const uint64_t* hb64 = (const uint64_t*)(hbF + ((t - 1) & 1) * HDIM);
      ((uint64_t*)s_h)[2 * tid]     = ald64(hb64 + 2 * tid);
      ((uint64_t*)s_h)[2 * tid + 1] = ald64(hb64 + 2 * tid + 1);
    } else {
      reinterpret_cast<float4*>(s_h)[tid] = reinterpret_cast<const float4*>(prev_h)[tid];
    }
    __syncthreads();

    float4 hf[8];
    #pragma unroll
    for (int k = 0; k < 8; ++k) hf[k] = reinterpret_cast<const float4*>(s_h)[k * 64 + lane];

    // ---- w_hh GEMV rows {j, H+j, 2H+j, 3H+j} (plain loads — 32KB slice stays L2-local) ----
    float gate[4];
    #pragma unroll
    for (int g = 0; g < 4; ++g) {
      const float4* wp = reinterpret_cast<const float4*>(w_hh + (size_t)(g * HDIM + j) * HDIM);
      float s = 0.f;
      #pragma unroll
      for (int k = 0; k < 8; ++k) {
        float4 b = wp[k * 64 + lane];
        s += b.x*hf[k].x + b.y*hf[k].y + b.z*hf[k].z + b.w*hf[k].w;
      }
      #pragma unroll
      for (int d = 1; d < 64; d <<= 1) s += __shfl_xor(s, d, 64);
      gate[g] = s;
    }

    // ---- REPLICATED SAMPLER: wv0 of EVERY block computes op(t-1) locally (bit-identical) ----
    if (t > 0 && wv == 0) {
      float dot = 0.f;
      #pragma unroll
      for (int c = 0; c < NC; ++c) {
        float s = (pp0[c] + pp1[c]) + (pp2[c] + pp3[c]);
        #pragma unroll
        for (int d = 1; d < 64; d <<= 1) s += __shfl_xor(s, d, 64);
        if (lane == c) dot = s;
      }
      const float logit = 2.5f * tanhf(dot * 0.2f);

      uint32_t k0, k1, bits;
      { uint32_t a = 0u, b = (uint32_t)(t - 1); tf2x32(0u, 42u, a, b); k0 = a; k1 = b; }
      { uint32_t a = 0u, b = (uint32_t)lane;    tf2x32(k0, k1, a, b); bits = a ^ b; }
      const float TINY = 1.175494350822287508e-38f;
      float f01 = __uint_as_float((bits >> 9) | 0x3f800000u) - 1.0f;
      float u = f01 * (1.0f - TINY) + TINY;
      u = fmaxf(TINY, u);
      const float gmb = -logf(-logf(u));

      float by = (lane < NC) ? (logit + gmb) : -1e30f;
      int   bi = (lane < NC) ? lane : 999;
      #pragma unroll
      for (int d = 1; d < 16; d <<= 1) {
        float oy = __shfl_xor(by, d, 16);
        int   oi = __shfl_xor(bi, d, 16);
        if (oy > by || (oy == by && oi < bi)) { by = oy; bi = oi; }
      }
      const int op = bi;

      if (blk == 0) {                                  // only block 0 writes outputs
        float m = (lane < NC) ? logit : -1e30f;
        #pragma unroll
        for (int d = 1; d < 16; d <<= 1) m = fmaxf(m, __shfl_xor(m, d, 16));
        const float sh = logit - m;
        float S = (lane < NC) ? expf(sh) : 0.f;
        #pragma unroll
        for (int d = 1; d < 16; d <<= 1) S += __shfl_xor(S, d, 16);
        const float lp = sh - logf(S);
        const float lp_op = __shfl(lp, op, 16);
        float tm = (lane < NC) ? expf(lp) * lp : 0.f;
        #pragma unroll
        for (int d = 1; d < 16; d <<= 1) tm += __shfl_xor(tm, d, 16);
        if (lane == 0) {
          out[t - 1] = (float)op + 0.002f;   // sentinel: 11.000=>never ran; k.002=>sync bug
          nll_acc += -lp_op;
          ent_acc += -tm;
        }
      }
      if (lane == 0) s_op = op;
    }
    __syncthreads();

    const int c_idx = (t == 0) ? 0 : ((s_op + 1 > NC - 1) ? NC - 1 : s_op + 1);

    const float iv = 1.f / (1.f + expf(-(gate[0] + s_E[wv][0][c_idx])));
    const float fv = 1.f / (1.f + expf(-(gate[1] + s_E[wv][1][c_idx])));
    const float gv = tanhf(gate[2] + s_E[wv][2][c_idx]);
    const float ov = 1.f / (1.f + expf(-(gate[3] + s_E[wv][3][c_idx])));
    c_val = fv * c_val + iv * gv;
    const float h_new = ov * tanhf(c_val);

    // ---- publish h slice + logit partials, then one-shot flag ----
    if (lane == 0) astf(hbF + (t & 1) * HDIM + j, h_new);
    if (lane < NC) s_part[wv][lane] = h_new * wsj;
    VMCNT0();                                          // own h store at coherence point
    __syncthreads();                                   // all waves' h stores + s_part done
    if (wv == 0) {
      if (lane < NC) {
        float p = ((s_part[0][lane] + s_part[1][lane]) + (s_part[2][lane] + s_part[3][lane]))
                + ((s_part[4][lane] + s_part[5][lane]) + (s_part[6][lane] + s_part[7][lane]));
        astf(partF + (t & 1) * (NC * NBLK) + lane * NBLK + blk, p);
      }
      VMCNT0();
      if (lane == 0) ast(flagsU + (size_t)t * NBLK + blk, FLAGMAGIC);
    }
  }

  // ---- epilogue: block 0 samples op(31) and writes final outputs ----
  if (blk == 0 && wv == 0) {
    {
      const uint32_t* f = flagsU + (size_t)(NL - 1) * NBLK;
      for (int it = 0; it < SPINCAP; ++it) {
        uint32_t a0 = ald(f + lane), a1 = ald(f + lane + 64),
                 a2 = ald(f + lane + 128), a3 = ald(f + lane + 192);
        bool ok = (a0 == FLAGMAGIC) & (a1 == FLAGMAGIC) & (a2 == FLAGMAGIC) & (a3 == FLAGMAGIC);
        if (__all(ok)) break;
      }
      CFENCE();
    }
    const float* pb = partF + ((NL - 1) & 1) * (NC * NBLK);
    float dot = 0.f;
    #pragma unroll
    for (int c = 0; c < NC; ++c) {
      float s = (aldf(pb + c * NBLK + lane)       + aldf(pb + c * NBLK + lane + 64))
              + (aldf(pb + c * NBLK + lane + 128) + aldf(pb + c * NBLK + lane + 192));
      #pragma unroll
      for (int d = 1; d < 64; d <<= 1) s += __shfl_xor(s, d, 64);
      if (lane == c) dot = s;
    }
    const float logit = 2.5f * tanhf(dot * 0.2f);

    uint32_t k0, k1, bits;
    { uint32_t a = 0u, b = (uint32_t)(NL - 1); tf2x32(0u, 42u, a, b); k0 = a; k1 = b; }
    { uint32_t a = 0u, b = (uint32_t)lane;     tf2x32(k0, k1, a, b); bits = a ^ b; }
    const float TINY = 1.175494350822287508e-38f;
    float f01 = __uint_as_float((bits >> 9) | 0x3f800000u) - 1.0f;
    float u = f01 * (1.0f - TINY) + TINY;
    u = fmaxf(TINY, u);
    const float gmb = -logf(-logf(u));

    float by = (lane < NC) ? (logit + gmb) : -1e30f;
    int   bi = (lane < NC) ? lane : 999;
    #pragma unroll
    for (int d = 1; d < 16; d <<= 1) {
      float oy = __shfl_xor(by, d, 16);
      int   oi = __shfl_xor(bi, d, 16);
      if (oy > by || (oy == by && oi < bi)) { by = oy; bi = oi; }
    }
    const int op = bi;

    float m = (lane < NC) ? logit : -1e30f;
    #pragma unroll
    for (int d = 1; d < 16; d <<= 1) m = fmaxf(m, __shfl_xor(m, d, 16));
    const float sh = logit - m;
    float S = (lane < NC) ? expf(sh) : 0.f;
    #pragma unroll
    for (int d = 1; d < 16; d <<= 1) S += __shfl_xor(S, d, 16);
    const float lp = sh - logf(S);
    const float lp_op = __shfl(lp, op, 16);
    float tm = (lane < NC) ? expf(lp) * lp : 0.f;
    #pragma unroll
    for (int d = 1; d < 16; d <<= 1) tm += __shfl_xor(tm, d, 16);

    if (lane == 0) {
      out[NL - 1] = (float)op + 0.002f;
      out[NL]     = nll_acc + (-lp_op);
      out[NL + 1] = ent_acc + (-tm);
    }
  }
}

extern "C" void kernel_launch(void* const* d_in, const int* in_sizes, int n_in,
                              void* d_out, int out_size, void* d_ws, size_t ws_size,
                              hipStream_t stream) {
  const float* prev_c  = (const float*)d_in[0];
  const float* prev_h  = (const float*)d_in[1];
  const float* encoder = (const float*)d_in[2];
  const float* w_ih    = (const float*)d_in[3];
  const float* w_hh    = (const float*)d_in[4];
  const float* b_ih    = (const float*)d_in[5];
  const float* b_hh    = (const float*)d_in[6];
  const float* w_soft  = (const float*)d_in[7];
  float* out = (float*)d_out;
  float* ws  = (float*)d_ws;   // ~72 KB used

  void* args[] = {&prev_c, &prev_h, &encoder, &w_ih, &w_hh, &b_ih, &b_hh, &w_soft, &out, &ws};
  hipError_t e = hipLaunchCooperativeKernel(reinterpret_cast<void*>(ctrl_kernel),
                                            dim3(NBLK), dim3(NTHR), args, 0, stream);
  if (e != hipSuccess) {
    // 256 blocks @ 1/CU are hardware-co-resident even without the cooperative API;
    // no grid.sync is used — flag protocol only — so plain launch is a valid fallback.
    ctrl_kernel<<<dim3(NBLK), dim3(NTHR), 0, stream>>>(prev_c, prev_h, encoder, w_ih, w_hh,
                                                       b_ih, b_hh, w_soft, out, ws);
  }
}

// Round 9
// 765.536 us; speedup vs baseline: 1.0821x; 1.0821x over previous
//
#include <hip/hip_runtime.h>
#include <stdint.h>

#define HDIM 2048
#define NC   12
#define NL   32
#define NBLK 256     // EXACTLY 256 blocks (1/CU) — proven-launchable config
#define NTHR 512     // 8 waves/block; wave (blk*8+wv) owns h-position j
#define NWAVE 8
#define SPINCAP 2000000          // bounded spin: bug => wrong answer, not hang
#define TAG(t) (0x600D0000u | (uint32_t)(t))   // never equals 0xAAAAAAAA poison

// ---------------- Threefry-2x32 (20 rounds), JAX partitionable path (verified r4) ----
__device__ __forceinline__ uint32_t rotl32(uint32_t x, int r) {
  return (x << r) | (x >> (32 - r));
}
__device__ __forceinline__ void tf2x32(uint32_t k0, uint32_t k1,
                                       uint32_t &x0, uint32_t &x1) {
  const uint32_t ks2 = k0 ^ k1 ^ 0x1BD11BDAu;
  x0 += k0; x1 += k1;
#define TFR(r) { x0 += x1; x1 = rotl32(x1, (r)); x1 ^= x0; }
  TFR(13) TFR(15) TFR(26) TFR(6)   x0 += k1;  x1 += ks2 + 1u;
  TFR(17) TFR(29) TFR(16) TFR(24)  x0 += ks2; x1 += k0  + 2u;
  TFR(13) TFR(15) TFR(26) TFR(6)   x0 += k0;  x1 += k1  + 3u;
  TFR(17) TFR(29) TFR(16) TFR(24)  x0 += k1;  x1 += ks2 + 4u;
  TFR(13) TFR(15) TFR(26) TFR(6)   x0 += ks2; x1 += k0  + 5u;
#undef TFR
}

// relaxed agent-scope atomics (device-coherent per access, no cache-wide maintenance)
__device__ __forceinline__ uint64_t ald64(const uint64_t* p) {
  return __hip_atomic_load(p, __ATOMIC_RELAXED, __HIP_MEMORY_SCOPE_AGENT);
}
__device__ __forceinline__ void ast64(uint64_t* p, uint64_t v) {
  __hip_atomic_store(p, v, __ATOMIC_RELAXED, __HIP_MEMORY_SCOPE_AGENT);
}
#define CFENCE() asm volatile("" ::: "memory")

// ws layout: hb uint64[2][HDIM] (32 KB) — the ONLY cross-block object.
// hb[t&1][j] = (TAG(t)<<32) | bits(h_t[j]); tags make period-2 reuse ABA-safe
// (skew proof: a block reaches post(t) only after every block posted t-1).
__global__ void __launch_bounds__(NTHR, 2) ctrl_kernel(
    const float* __restrict__ prev_c, const float* __restrict__ prev_h,
    const float* __restrict__ encoder, const float* __restrict__ w_ih,
    const float* __restrict__ w_hh, const float* __restrict__ b_ih,
    const float* __restrict__ b_hh, const float* __restrict__ w_soft,
    float* __restrict__ out, float* __restrict__ ws)
{
  const int tid  = threadIdx.x;
  const int lane = tid & 63;
  const int wv   = tid >> 6;
  const int blk  = blockIdx.x;
  const int j    = blk * NWAVE + wv;                   // owned h-position

  uint64_t* hb = (uint64_t*)ws;                        // [2][HDIM]

  __shared__ __align__(16) float s_h[HDIM];
  __shared__ float s_E[NWAVE][4][NC];
  __shared__ float s_dot[16];
  __shared__ int   s_op;

  if (tid < 16) s_dot[tid] = 0.f;

  // one-time E[c][g] = encoder[c] . w_ih_row(g,j) + b_ih + b_hh  (w_ih read exactly once)
  {
    float4 wif[4][8];
    #pragma unroll
    for (int g = 0; g < 4; ++g) {
      const float4* wp = reinterpret_cast<const float4*>(w_ih + (size_t)(g * HDIM + j) * HDIM);
      #pragma unroll
      for (int k = 0; k < 8; ++k) wif[g][k] = wp[k * 64 + lane];
    }
    float bsum[4];
    #pragma unroll
    for (int g = 0; g < 4; ++g) bsum[g] = b_ih[g * HDIM + j] + b_hh[g * HDIM + j];

    for (int c = 0; c < NC; ++c) {
      const float4* ep = reinterpret_cast<const float4*>(encoder + (size_t)c * HDIM);
      float s0 = 0.f, s1 = 0.f, s2 = 0.f, s3 = 0.f;
      #pragma unroll
      for (int k = 0; k < 8; ++k) {
        float4 e = ep[k * 64 + lane];
        s0 += wif[0][k].x*e.x + wif[0][k].y*e.y + wif[0][k].z*e.z + wif[0][k].w*e.w;
        s1 += wif[1][k].x*e.x + wif[1][k].y*e.y + wif[1][k].z*e.z + wif[1][k].w*e.w;
        s2 += wif[2][k].x*e.x + wif[2][k].y*e.y + wif[2][k].z*e.z + wif[2][k].w*e.w;
        s3 += wif[3][k].x*e.x + wif[3][k].y*e.y + wif[3][k].z*e.z + wif[3][k].w*e.w;
      }
      #pragma unroll
      for (int d = 1; d < 64; d <<= 1) {
        s0 += __shfl_xor(s0, d, 64); s1 += __shfl_xor(s1, d, 64);
        s2 += __shfl_xor(s2, d, 64); s3 += __shfl_xor(s3, d, 64);
      }
      if (lane == 0) {
        s_E[wv][0][c] = s0 + bsum[0]; s_E[wv][1][c] = s1 + bsum[1];
        s_E[wv][2][c] = s2 + bsum[2]; s_E[wv][3][c] = s3 + bsum[3];
      }
    }
  }
  __syncthreads();

  float c_val   = prev_c[j];
  float nll_acc = 0.f, ent_acc = 0.f;                  // meaningful in blk0/wv0/lane0 only

  for (int t = 0; t <= NL; ++t) {
    // ---- A: stage h(t-1) into LDS (tag-polled; no flags, no separate data read) ----
    if (t == 0) {
      reinterpret_cast<float4*>(s_h)[tid] = reinterpret_cast<const float4*>(prev_h)[tid];
    } else {
      const uint64_t* base = hb + ((t - 1) & 1) * HDIM + wv * 256;
      const uint32_t want = TAG(t - 1);
      uint64_t v0 = 0, v1 = 0, v2 = 0, v3 = 0;
      for (int it = 0; it < SPINCAP; ++it) {
        v0 = ald64(base + lane);       v1 = ald64(base + lane + 64);
        v2 = ald64(base + lane + 128); v3 = ald64(base + lane + 192);
        bool ok = ((uint32_t)(v0 >> 32) == want) & ((uint32_t)(v1 >> 32) == want)
                & ((uint32_t)(v2 >> 32) == want) & ((uint32_t)(v3 >> 32) == want);
        if (__all(ok)) break;
      }
      CFENCE();
      s_h[wv * 256 + lane]       = __uint_as_float((uint32_t)v0);
      s_h[wv * 256 + lane + 64]  = __uint_as_float((uint32_t)v1);
      s_h[wv * 256 + lane + 128] = __uint_as_float((uint32_t)v2);
      s_h[wv * 256 + lane + 192] = __uint_as_float((uint32_t)v3);
    }
    __syncthreads();

    // ---- B: local logits of h(t-1): dot[c] = s_h . w_soft[c]  (w_soft is L2-cached) ----
    if (t > 0) {
      const int c0 = wv, c1 = wv + 8;
      const float4* sh4 = reinterpret_cast<const float4*>(s_h);
      const float4* wsA = reinterpret_cast<const float4*>(w_soft + (size_t)c0 * HDIM);
      const float4* wsB = reinterpret_cast<const float4*>(w_soft + (size_t)(c1 < NC ? c1 : 0) * HDIM);
      float d0 = 0.f, d1 = 0.f;
      #pragma unroll
      for (int k = 0; k < 8; ++k) {
        float4 h4 = sh4[k * 64 + lane];
        float4 a  = wsA[k * 64 + lane];
        d0 += a.x*h4.x + a.y*h4.y + a.z*h4.z + a.w*h4.w;
        if (c1 < NC) {
          float4 b = wsB[k * 64 + lane];
          d1 += b.x*h4.x + b.y*h4.y + b.z*h4.z + b.w*h4.w;
        }
      }
      #pragma unroll
      for (int d = 1; d < 64; d <<= 1) {
        d0 += __shfl_xor(d0, d, 64);
        d1 += __shfl_xor(d1, d, 64);
      }
      if (lane == 0) {
        s_dot[c0] = d0;
        if (c1 < NC) s_dot[c1] = d1;
      }
    }
    __syncthreads();

    // ---- C: replicated sampler on wv0 (identical FP in every block => identical op);
    //         meanwhile wv1..7 proceed to the GEMV, hiding the sampling latency ----
    if (t > 0 && wv == 0) {
      const int tt = t - 1;
      const float logit = (lane < NC) ? 2.5f * tanhf(s_dot[lane] * 0.2f) : 0.f;

      uint32_t k0, k1, bits;
      { uint32_t a = 0u, b = (uint32_t)tt;   tf2x32(0u, 42u, a, b); k0 = a; k1 = b; }
      { uint32_t a = 0u, b = (uint32_t)lane; tf2x32(k0, k1, a, b); bits = a ^ b; }
      const float TINY = 1.175494350822287508e-38f;
      float f01 = __uint_as_float((bits >> 9) | 0x3f800000u) - 1.0f;
      float u = f01 * (1.0f - TINY) + TINY;
      u = fmaxf(TINY, u);
      const float gmb = -logf(-logf(u));

      float by = (lane < NC) ? (logit + gmb) : -1e30f;
      int   bi = (lane < NC) ? lane : 999;
      #pragma unroll
      for (int d = 1; d < 16; d <<= 1) {
        float oy = __shfl_xor(by, d, 16);
        int   oi = __shfl_xor(bi, d, 16);
        if (oy > by || (oy == by && oi < bi)) { by = oy; bi = oi; }
      }
      const int op = bi;

      if (blk == 0) {                                  // only block 0 writes outputs
        float m = (lane < NC) ? logit : -1e30f;
        #pragma unroll
        for (int d = 1; d < 16; d <<= 1) m = fmaxf(m, __shfl_xor(m, d, 16));
        const float sh = logit - m;
        float S = (lane < NC) ? expf(sh) : 0.f;
        #pragma unroll
        for (int d = 1; d < 16; d <<= 1) S += __shfl_xor(S, d, 16);
        const float lp = sh - logf(S);
        const float lp_op = __shfl(lp, op, 16);
        float tm = (lane < NC) ? expf(lp) * lp : 0.f;
        #pragma unroll
        for (int d = 1; d < 16; d <<= 1) tm += __shfl_xor(tm, d, 16);
        if (lane == 0) {
          out[tt] = (float)op + 0.002f;   // sentinel: 11.000=>never ran; k.002=>sync bug
          nll_acc += -lp_op;
          ent_acc += -tm;
          if (t == NL) { out[NL] = nll_acc; out[NL + 1] = ent_acc; }
        }
      }
      if (lane == 0) s_op = op;
    }
    if (t == NL) break;                                // epilogue iteration: sample(31) only

    // ---- D: w_hh GEMV rows {j, H+j, 2H+j, 3H+j} (plain loads — 32KB slice stays L2-warm) ----
    float4 hf[8];
    #pragma unroll
    for (int k = 0; k < 8; ++k) hf[k] = reinterpret_cast<const float4*>(s_h)[k * 64 + lane];
    float gate[4];
    #pragma unroll
    for (int g = 0; g < 4; ++g) {
      const float4* wp = reinterpret_cast<const float4*>(w_hh + (size_t)(g * HDIM + j) * HDIM);
      float s = 0.f;
      #pragma unroll
      for (int k = 0; k < 8; ++k) {
        float4 b = wp[k * 64 + lane];
        s += b.x*hf[k].x + b.y*hf[k].y + b.z*hf[k].z + b.w*hf[k].w;
      }
      #pragma unroll
      for (int d = 1; d < 64; d <<= 1) s += __shfl_xor(s, d, 64);
      gate[g] = s;
    }
    __syncthreads();                                   // s_op (written pre-GEMV by wv0) now visible

    const int c_idx = (t == 0) ? 0 : ((s_op + 1 > NC - 1) ? NC - 1 : s_op + 1);

    const float iv = 1.f / (1.f + expf(-(gate[0] + s_E[wv][0][c_idx])));
    const float fv = 1.f / (1.f + expf(-(gate[1] + s_E[wv][1][c_idx])));
    const float gv = tanhf(gate[2] + s_E[wv][2][c_idx]);
    const float ov = 1.f / (1.f + expf(-(gate[3] + s_E[wv][3][c_idx])));
    c_val = fv * c_val + iv * gv;
    const float h_new = ov * tanhf(c_val);

    // ---- E: publish tagged h — ONE 8-byte relaxed agent store, fire-and-forget ----
    if (lane == 0) {
      uint64_t w = ((uint64_t)TAG(t) << 32) | (uint64_t)__float_as_uint(h_new);
      ast64(hb + (t & 1) * HDIM + j, w);
    }
  }
}

extern "C" void kernel_launch(void* const* d_in, const int* in_sizes, int n_in,
                              void* d_out, int out_size, void* d_ws, size_t ws_size,
                              hipStream_t stream) {
  const float* prev_c  = (const float*)d_in[0];
  const float* prev_h  = (const float*)d_in[1];
  const float* encoder = (const float*)d_in[2];
  const float* w_ih    = (const float*)d_in[3];
  const float* w_hh    = (const float*)d_in[4];
  const float* b_ih    = (const float*)d_in[5];
  const float* b_hh    = (const float*)d_in[6];
  const float* w_soft  = (const float*)d_in[7];
  float* out = (float*)d_out;
  float* ws  = (float*)d_ws;   // 32 KB used (tagged h double-buffer)

  void* args[] = {&prev_c, &prev_h, &encoder, &w_ih, &w_hh, &b_ih, &b_hh, &w_soft, &out, &ws};
  hipError_t e = hipLaunchCooperativeKernel(reinterpret_cast<void*>(ctrl_kernel),
                                            dim3(NBLK), dim3(NTHR), args, 0, stream);
  if (e != hipSuccess) {
    // 256 blocks @ 1/CU are hardware-co-resident even without the cooperative API;
    // no grid.sync is used — tag protocol only — so plain launch is a valid fallback.
    ctrl_kernel<<<dim3(NBLK), dim3(NTHR), 0, stream>>>(prev_c, prev_h, encoder, w_ih, w_hh,
                                                       b_ih, b_hh, w_soft, out, ws);
  }
}